// Round 3
// baseline (245.917 us; speedup 1.0000x reference)
//
#include <hip/hip_runtime.h>

#define GAS __attribute__((address_space(1)))
#define LAS __attribute__((address_space(3)))

typedef __attribute__((ext_vector_type(8))) short short8;
typedef __attribute__((ext_vector_type(4))) short short4_t;
typedef __attribute__((ext_vector_type(4))) float f32x4;
typedef unsigned short u16;

constexpr int cB = 16, cC = 256, cIC = 128, cN = 1024;

__device__ __forceinline__ u16 f2bf(float v) {
    unsigned u = __builtin_bit_cast(unsigned, v);
    return (u16)((u + 0x7fffu + ((u >> 16) & 1u)) >> 16);
}
__device__ __forceinline__ float bf2f(u16 v) {
    unsigned u = ((unsigned)v) << 16;
    return __builtin_bit_cast(float, u);
}

template<int N> __device__ __forceinline__ void wait_vmcnt() {
    if constexpr (N == 0) asm volatile("s_waitcnt vmcnt(0)" ::: "memory");
    else if constexpr (N == 2) asm volatile("s_waitcnt vmcnt(2)" ::: "memory");
    else if constexpr (N == 3) asm volatile("s_waitcnt vmcnt(3)" ::: "memory");
    else if constexpr (N == 4) asm volatile("s_waitcnt vmcnt(4)" ::: "memory");
    else if constexpr (N == 6) asm volatile("s_waitcnt vmcnt(6)" ::: "memory");
}

// ---------------------------------------------------------------------------
// Double-buffered prefetch GEMM core with LDS XOR-swizzle.
// C[m,n] = sum_k A[m,k]*B[n,k]  (both K-major). SYMB: B k-index XOR 128.
// Swizzle: 16B slot within a row's 64B K-chunk is XOR'd by (row>>1)&3;
// applied on the global SOURCE address at stage time (LDS dest stays linear,
// required by global_load_lds) and on the ds_read address. 2-way conflicts.
// ---------------------------------------------------------------------------
template<int BM, int BN, int WR, int WC, bool SYMB>
__device__ __forceinline__ void gemm_core(
    const u16* __restrict__ Ab, int lda,
    const u16* __restrict__ Bb, int ldb, int K,
    u16* lsA, u16* lsB,
    f32x4 (&acc)[BM/(WR*16)][BN/(WC*16)])
{
    constexpr int THREADS = WR * WC * 64;
    constexpr int MR = BM / (WR * 16), NR = BN / (WC * 16);
    constexpr int ACH = (BM * 64) / (THREADS * 16);
    constexpr int BCH = (BN * 64) / (THREADS * 16);
    constexpr int RPC = THREADS / 4;
    constexpr int ISSUES = ACH + BCH;

    const int tid  = threadIdx.x;
    const int lane = tid & 63;
    const int wave = tid >> 6;
    const int wr = wave / WC, wc = wave % WC;
    const int r0 = tid >> 2, slot = tid & 3;

    auto stage = [&](int buf, int kk) {
        const u16* Ak = Ab + kk;
        const u16* Bk = Bb + (SYMB ? (kk ^ 128) : kk);
        #pragma unroll
        for (int c = 0; c < ACH; c++) {
            int row = c * RPC + r0;
            int sk = (slot ^ ((row >> 1) & 3)) << 3;
            __builtin_amdgcn_global_load_lds((GAS void*)(Ak + (size_t)row * lda + sk),
                (LAS void*)(lsA + buf * (BM * 32) + c * (THREADS * 8) + (wave << 9)), 16, 0, 0);
        }
        #pragma unroll
        for (int c = 0; c < BCH; c++) {
            int row = c * RPC + r0;
            int sk = (slot ^ ((row >> 1) & 3)) << 3;
            __builtin_amdgcn_global_load_lds((GAS void*)(Bk + (size_t)row * ldb + sk),
                (LAS void*)(lsB + buf * (BN * 32) + c * (THREADS * 8) + (wave << 9)), 16, 0, 0);
        }
    };

    stage(0, 0);
    const int nt = K >> 5;
    for (int t = 0; t < nt; t++) {
        const int cur = t & 1;
        if (t + 1 < nt) { stage(cur ^ 1, (t + 1) << 5); wait_vmcnt<ISSUES>(); }
        else            wait_vmcnt<0>();
        __builtin_amdgcn_s_barrier();
        asm volatile("" ::: "memory");

        const u16* la = lsA + cur * (BM * 32);
        const u16* lb = lsB + cur * (BN * 32);
        short8 af[MR], bf[NR];
        #pragma unroll
        for (int m = 0; m < MR; m++) {
            int row = wr * (BM / WR) + (m << 4) + (lane & 15);
            af[m] = *(const short8*)&la[(row << 5) + (((lane >> 4) ^ ((row >> 1) & 3)) << 3)];
        }
        #pragma unroll
        for (int n = 0; n < NR; n++) {
            int row = wc * (BN / WC) + (n << 4) + (lane & 15);
            bf[n] = *(const short8*)&lb[(row << 5) + (((lane >> 4) ^ ((row >> 1) & 3)) << 3)];
        }
        #pragma unroll
        for (int m = 0; m < MR; m++)
            #pragma unroll
            for (int n = 0; n < NR; n++)
                acc[m][n] = __builtin_amdgcn_mfma_f32_16x16x32_bf16(af[m], bf[n], acc[m][n], 0, 0, 0);

        asm volatile("s_waitcnt lgkmcnt(0)" ::: "memory");
        __builtin_amdgcn_sched_barrier(0);
        __builtin_amdgcn_s_barrier();
    }
}

// ---------------------------------------------------------------------------
// Generic GEMM wrapper. z decomposed zlo=z&15, zhi=z>>4.
// ---------------------------------------------------------------------------
template<int BM, int BN, int WR, int WC, bool RELU, bool OBF16, bool RBIAS, bool RESID>
__global__ __launch_bounds__(WR*WC*64) void gemm_bt(
    const u16* __restrict__ A, long long sA, long long sA2, int lda,
    const u16* __restrict__ B, long long sB, long long sB2, int ldb,
    void* __restrict__ C, long long sC, long long sC2, int ldc,
    int K,
    const float* __restrict__ bias, int sb2,
    const float* __restrict__ resid, long long sR)
{
    __shared__ alignas(16) u16 lsA[2 * BM * 32];
    __shared__ alignas(16) u16 lsB[2 * BN * 32];

    const int lane = threadIdx.x & 63;
    const int wave = threadIdx.x >> 6;
    const int wr = wave / WC, wc = wave % WC;
    const int zlo = blockIdx.z & 15, zhi = blockIdx.z >> 4;

    const u16* Ab = A + zlo * sA + zhi * sA2 + (size_t)(blockIdx.x * BM) * lda;
    const u16* Bb = B + zlo * sB + zhi * sB2 + (size_t)(blockIdx.y * BN) * ldb;

    f32x4 acc[BM/(WR*16)][BN/(WC*16)] = {};
    gemm_core<BM, BN, WR, WC, false>(Ab, lda, Bb, ldb, K, lsA, lsB, acc);

    const int rowb = blockIdx.x * BM + wr * (BM / WR) + ((lane >> 4) << 2);
    const int colb = blockIdx.y * BN + wc * (BN / WC) + (lane & 15);
    const long long cbase = zlo * sC + zhi * sC2;
    #pragma unroll
    for (int m = 0; m < BM/(WR*16); m++) {
        #pragma unroll
        for (int n = 0; n < BN/(WC*16); n++) {
            #pragma unroll
            for (int r = 0; r < 4; r++) {
                int row = rowb + m * 16 + r;
                int col = colb + n * 16;
                float v = acc[m][n][r];
                if (RBIAS) v += bias[zhi * sb2 + row];
                if (RESID) v += resid[zlo * sR + (size_t)row * ldc + col];
                if (RELU)  v = fmaxf(v, 0.0f);
                if (OBF16) ((u16*)C)[cbase + (size_t)row * ldc + col] = f2bf(v);
                else       ((float*)C)[cbase + (size_t)row * ldc + col] = v;
            }
        }
    }
}

// ---------------------------------------------------------------------------
// Symmetric attention GEMM, triangle tiles only. S = 0.5*(t p^T + p t^T),
// bf16 out, direct + transposed tile writes, fused degree row-sums.
// A = B = TP[z] ([1024][256], t|p); SYMB XOR gives (p|t).
// ---------------------------------------------------------------------------
__global__ __launch_bounds__(256) void sym_gemm(
    const u16* __restrict__ TP, u16* __restrict__ S, float* __restrict__ rsum)
{
    __shared__ alignas(16) u16 lsA[2 * 128 * 32];
    __shared__ alignas(16) u16 lsB[2 * 128 * 32];

    const int t = blockIdx.x;               // 0..35 triangular index
    int bx = (int)((sqrtf(8.0f * t + 1.01f) - 1.0f) * 0.5f);
    while ((bx + 1) * (bx + 2) / 2 <= t) bx++;
    while (bx * (bx + 1) / 2 > t) bx--;
    const int by = t - bx * (bx + 1) / 2;
    const int z = blockIdx.z;

    const u16* TPz = TP + (size_t)z * 262144;
    const u16* Ab = TPz + (size_t)(bx * 128) * 256;
    const u16* Bb = TPz + (size_t)(by * 128) * 256;

    f32x4 acc[4][4] = {};
    gemm_core<128, 128, 2, 2, true>(Ab, 256, Bb, 256, 256, lsA, lsB, acc);

    const int lane = threadIdx.x & 63;
    const int wave = threadIdx.x >> 6;
    const int wr = wave >> 1, wc = wave & 1;
    const int rowb = bx * 128 + (wr << 6) + ((lane >> 4) << 2);
    const int colb = by * 128 + (wc << 6) + (lane & 15);
    u16* Sz = S + ((size_t)z << 20);
    float* rz = rsum + (z << 10);

    float rp[4][4] = {};
    float cp[4] = {};
    #pragma unroll
    for (int m = 0; m < 4; m++) {
        #pragma unroll
        for (int n = 0; n < 4; n++) {
            #pragma unroll
            for (int r = 0; r < 4; r++) {
                int row = rowb + m * 16 + r;
                int col = colb + n * 16;
                float v = acc[m][n][r] * 0.5f;
                Sz[((size_t)row << 10) + col] = f2bf(v);
                rp[m][r] += v;
                cp[n] += v;
            }
        }
    }
    // direct row sums (rows of this tile, over its 128 cols per... 64 cols/wave)
    #pragma unroll
    for (int m = 0; m < 4; m++) {
        #pragma unroll
        for (int r = 0; r < 4; r++) {
            float v = rp[m][r];
            v += __shfl_xor(v, 1, 64);
            v += __shfl_xor(v, 2, 64);
            v += __shfl_xor(v, 4, 64);
            v += __shfl_xor(v, 8, 64);
            if ((lane & 15) == 0) atomicAdd(&rz[rowb + m * 16 + r], v);
        }
    }
    if (bx != by) {
        // transposed tile write: S[col][row] (8B contiguous per thread)
        #pragma unroll
        for (int m = 0; m < 4; m++) {
            #pragma unroll
            for (int n = 0; n < 4; n++) {
                short4_t w;
                #pragma unroll
                for (int r = 0; r < 4; r++) w[r] = (short)f2bf(acc[m][n][r] * 0.5f);
                int col = colb + n * 16;
                *(short4_t*)&Sz[((size_t)col << 10) + rowb + m * 16] = w;
            }
        }
        // column sums -> row sums of the transposed region
        #pragma unroll
        for (int n = 0; n < 4; n++) {
            float v = cp[n];
            v += __shfl_xor(v, 16, 64);
            v += __shfl_xor(v, 32, 64);
            if ((lane >> 4) == 0) atomicAdd(&rz[colb + n * 16], v);
        }
    }
}

// ---------------------------------------------------------------------------
// g-conv with fused dinv scaling: g = Wg@X + bg, then write scaled copies.
// zhi==0 (g_x) writes 3 dests (dinv_x, dinv_b, dinv_d).
// ---------------------------------------------------------------------------
__global__ __launch_bounds__(256) void g_conv(
    const u16* __restrict__ WG, const u16* __restrict__ XT,
    const float* __restrict__ BG, const float* __restrict__ DINV,
    u16* __restrict__ GXp, u16* __restrict__ GBp, u16* __restrict__ GDp)
{
    __shared__ alignas(16) u16 lsA[2 * 128 * 32];
    __shared__ alignas(16) u16 lsB[2 * 128 * 32];

    const int zlo = blockIdx.z & 15, zhi = blockIdx.z >> 4;
    const u16* Ab = WG + zhi * 32768;
    const u16* Bb = XT + (size_t)zhi * 4194304 + (size_t)zlo * 262144 + (size_t)(blockIdx.y * 128) * 256;

    f32x4 acc[4][4] = {};
    gemm_core<128, 128, 2, 2, false>(Ab, 256, Bb, 256, 256, lsA, lsB, acc);

    const int lane = threadIdx.x & 63;
    const int wave = threadIdx.x >> 6;
    const int wr = wave >> 1, wc = wave & 1;
    const int rowb = (wr << 6) + ((lane >> 4) << 2);
    const int colb = blockIdx.y * 128 + (wc << 6) + (lane & 15);
    const float* dvx = DINV + (zlo << 10);
    const float* dvb = DINV + 16384 + (zlo << 10);
    const float* dvd = DINV + 32768 + (zlo << 10);

    #pragma unroll
    for (int m = 0; m < 4; m++) {
        #pragma unroll
        for (int n = 0; n < 4; n++) {
            #pragma unroll
            for (int r = 0; r < 4; r++) {
                int row = rowb + m * 16 + r;
                int col = colb + n * 16;
                float v = acc[m][n][r] + BG[zhi * 128 + row];
                size_t i128 = (size_t)zlo * 131072 + ((size_t)row << 10) + col;
                size_t i256 = (size_t)zlo * 262144 + ((size_t)row << 10) + col;
                size_t i256h = (size_t)zlo * 262144 + ((size_t)(row + 128) << 10) + col;
                if (zhi == 0) {
                    GXp[i128]  = f2bf(v * dvx[col]);
                    GBp[i256h] = f2bf(v * dvb[col]);
                    GDp[i256h] = f2bf(v * dvd[col]);
                } else if (zhi == 1) {
                    GBp[i256] = f2bf(v * dvb[col]);
                } else {
                    GDp[i256] = f2bf(v * dvd[col]);
                }
            }
        }
    }
}

// ---------------------------------------------------------------------------
// Aggregation for b/d streams: h = S_bf16 @ G^T, *dinv[row].
// One 128x256 tile per block (8 waves); cols<128 -> self dest, >=128 cross.
// ---------------------------------------------------------------------------
__global__ __launch_bounds__(512) void agg_bd(
    const u16* __restrict__ S, const u16* __restrict__ GBp, const u16* __restrict__ GDp,
    const float* __restrict__ DINV,
    u16* __restrict__ HS1, u16* __restrict__ HS2)
{
    __shared__ alignas(16) u16 lsA[2 * 128 * 32];
    __shared__ alignas(16) u16 lsB[2 * 256 * 32];

    const int z = blockIdx.z;               // 0..31
    const int which = z >> 4;               // 0: f_b, 1: f_d
    const int b = z & 15;
    const u16* Ab = S + ((size_t)(16 + z) << 20) + (size_t)(blockIdx.x * 128) * 1024;
    const u16* Bb = (which ? GDp : GBp) + (size_t)b * 262144;

    f32x4 acc[4][4] = {};
    gemm_core<128, 256, 2, 4, false>(Ab, 1024, Bb, 1024, 1024, lsA, lsB, acc);

    const int lane = threadIdx.x & 63;
    const int wave = threadIdx.x >> 6;
    const int wr = wave >> 2, wc = wave & 3;
    const int rowb = blockIdx.x * 128 + (wr << 6) + ((lane >> 4) << 2);
    const int colb = (wc << 6) + (lane & 15);
    const float* dv = DINV + (1 + which) * 16384 + (b << 10);
    u16* Cself  = (which ? HS1 : HS2) + (size_t)b * 262144;
    u16* Ccross = (which ? HS2 : HS1) + (size_t)b * 262144;
    u16* Cw = (wc < 2) ? Cself : Ccross;

    #pragma unroll
    for (int m = 0; m < 4; m++) {
        #pragma unroll
        for (int n = 0; n < 4; n++) {
            #pragma unroll
            for (int r = 0; r < 4; r++) {
                int row = rowb + m * 16 + r;
                int col = colb + n * 16;
                Cw[((size_t)row << 8) + col] = f2bf(acc[m][n][r] * dv[row]);
            }
        }
    }
}

// ---------------------------------------------------------------------------
// Aggregation for the x stream: HX = S_x @ GXp^T, *dinv_x[row].
// ---------------------------------------------------------------------------
__global__ __launch_bounds__(256) void agg_x(
    const u16* __restrict__ S, const u16* __restrict__ GXp,
    const float* __restrict__ DINV, u16* __restrict__ HX)
{
    __shared__ alignas(16) u16 lsA[2 * 128 * 32];
    __shared__ alignas(16) u16 lsB[2 * 128 * 32];

    const int b = blockIdx.z;
    const u16* Ab = S + ((size_t)b << 20) + (size_t)(blockIdx.x * 128) * 1024;
    const u16* Bb = GXp + (size_t)b * 131072;

    f32x4 acc[4][4] = {};
    gemm_core<128, 128, 2, 2, false>(Ab, 1024, Bb, 1024, 1024, lsA, lsB, acc);

    const int lane = threadIdx.x & 63;
    const int wave = threadIdx.x >> 6;
    const int wr = wave >> 1, wc = wave & 1;
    const int rowb = blockIdx.x * 128 + (wr << 6) + ((lane >> 4) << 2);
    const int colb = (wc << 6) + (lane & 15);
    const float* dv = DINV + (b << 10);
    u16* Cb = HX + (size_t)b * 131072;

    #pragma unroll
    for (int m = 0; m < 4; m++)
        #pragma unroll
        for (int n = 0; n < 4; n++)
            #pragma unroll
            for (int r = 0; r < 4; r++) {
                int row = rowb + m * 16 + r;
                int col = colb + n * 16;
                Cb[((size_t)row << 7) + col] = f2bf(acc[m][n][r] * dv[row]);
            }
}

// ---------------------------------------------------------------------------
__global__ void transpose_cast(const float* __restrict__ x, const float* __restrict__ ob,
                               const float* __restrict__ od, u16* __restrict__ xt)
{
    __shared__ float t[32][33];
    int z = blockIdx.z, which = z >> 4, b = z & 15;
    const float* src = (which == 0) ? x : (which == 1) ? ob : od;
    const float* s = src + (size_t)b * cC * cN;
    u16* dst = xt + (size_t)which * (cB * cN * cC) + (size_t)b * (cN * cC);
    int n0 = blockIdx.x << 5, c0 = blockIdx.y << 5;
    int tx = threadIdx.x, ty = threadIdx.y;
    #pragma unroll
    for (int i = 0; i < 4; i++) { int r = ty + (i << 3); t[r][tx] = s[(size_t)(c0 + r) * cN + n0 + tx]; }
    __syncthreads();
    #pragma unroll
    for (int i = 0; i < 4; i++) { int r = ty + (i << 3); dst[(size_t)(n0 + r) * cC + c0 + tx] = f2bf(t[tx][r]); }
}

__global__ void prep_weights(const float* Wt, const float* Wp,
                             const float* Wgx, const float* Wgb, const float* Wgd,
                             const float* bgx, const float* bgb, const float* bgd,
                             const float* Wwd, const float* Wwxb, const float* Wwb, const float* Wwxd,
                             const float* Wwx, const float* Wout,
                             u16* wtp, u16* wg, u16* ww1, u16* ww2, u16* wwx, u16* wout,
                             float* bg)
{
    int t = blockIdx.x * 256 + threadIdx.x;   // 65536
    wtp[t]  = f2bf(t < 32768 ? Wt[t] : Wp[t - 32768]);
    wout[t] = f2bf(Wout[t]);
    {
        int o = t >> 8, c = t & 255;
        ww1[t] = f2bf(c < 128 ? Wwd[(o << 7) + c] : Wwxb[(o << 7) + c - 128]);
        ww2[t] = f2bf(c < 128 ? Wwb[(o << 7) + c] : Wwxd[(o << 7) + c - 128]);
    }
    if (t < 32768) {
        wg[t] = f2bf(Wgx[t]); wg[32768 + t] = f2bf(Wgb[t]); wg[65536 + t] = f2bf(Wgd[t]);
        wwx[t] = f2bf(Wwx[t]);
    }
    if (t < 384) bg[t] = (t < 128) ? bgx[t] : (t < 256) ? bgb[t - 128] : bgd[t - 256];
}

__global__ void make_dinv(const float* __restrict__ rs, float* __restrict__ dinv)
{
    int i = blockIdx.x * 256 + threadIdx.x;   // 49152
    float d = rs[i];
    dinv[i] = (d != 0.0f) ? rsqrtf(d) : 0.0f;
}

__global__ void bn_stats(const u16* __restrict__ s1, const u16* __restrict__ s2,
                         float* __restrict__ acc)
{
    int c = threadIdx.x;
    const u16* s = blockIdx.y ? s2 : s1;
    float* a = acc + blockIdx.y * 512;
    size_t r0 = (size_t)blockIdx.x * 64;
    float sum = 0, sq = 0;
    for (int r = 0; r < 64; r++) { float v = bf2f(s[(r0 + r) * 256 + c]); sum += v; sq += v * v; }
    atomicAdd(&a[c], sum);
    atomicAdd(&a[256 + c], sq);
}

__global__ void bn_finalize(const float* __restrict__ acc,
                            const float* g1, const float* b1,
                            const float* g2, const float* b2,
                            float* __restrict__ p)
{
    int c = threadIdx.x;
    const float inv = 1.0f / 16384.0f;
    for (int k = 0; k < 2; k++) {
        float mean = acc[k * 512 + c] * inv;
        float var  = acc[k * 512 + 256 + c] * inv - mean * mean;
        const float* g = k ? g2 : g1;
        const float* be = k ? b2 : b1;
        float sc = g[c] * rsqrtf(var + 1e-5f);
        p[k * 512 + c] = sc;
        p[k * 512 + 256 + c] = be[c] - mean * sc;
    }
}

__global__ void combine_kernel(const u16* __restrict__ s1, const u16* __restrict__ s2,
                               const u16* __restrict__ xs, const float* __restrict__ p,
                               const float* __restrict__ bwx, u16* __restrict__ pre)
{
    size_t t = (size_t)blockIdx.x * 256 + threadIdx.x;   // 524288
    size_t base = t << 3;
    int c0 = (int)(base & 255);
    short8 a = *(const short8*)(s1 + base);
    short8 b = *(const short8*)(s2 + base);
    short8 cx = *(const short8*)(xs + base);
    short8 o;
    #pragma unroll
    for (int j = 0; j < 8; j++) {
        int c = c0 + j;
        float v = p[c] * bf2f((u16)a[j]) + p[256 + c]
                + p[512 + c] * bf2f((u16)b[j]) + p[768 + c]
                + bf2f((u16)cx[j]) + bwx[c];
        o[j] = (short)f2bf(v);
    }
    *(short8*)(pre + base) = o;
}

// ---------------------------------------------------------------------------
extern "C" void kernel_launch(void* const* d_in, const int* in_sizes, int n_in,
                              void* d_out, int out_size, void* d_ws, size_t ws_size,
                              hipStream_t stream)
{
    const float* x    = (const float*)d_in[0];
    const float* ob   = (const float*)d_in[1];
    const float* od   = (const float*)d_in[2];
    const float* Wt   = (const float*)d_in[3];
    const float* Wp   = (const float*)d_in[4];
    const float* Wgx  = (const float*)d_in[5];
    const float* bgx  = (const float*)d_in[6];
    const float* Wgb  = (const float*)d_in[7];
    const float* bgb  = (const float*)d_in[8];
    const float* Wgd  = (const float*)d_in[9];
    const float* bgd  = (const float*)d_in[10];
    const float* Wwx  = (const float*)d_in[11];
    const float* bwx  = (const float*)d_in[12];
    const float* Wwb  = (const float*)d_in[13];
    const float* Wwd  = (const float*)d_in[15];
    const float* Wwxb = (const float*)d_in[17];
    const float* Wwxd = (const float*)d_in[19];
    const float* g1   = (const float*)d_in[21];
    const float* be1  = (const float*)d_in[22];
    const float* g2   = (const float*)d_in[23];
    const float* be2  = (const float*)d_in[24];
    const float* Wout = (const float*)d_in[25];
    const float* bout = (const float*)d_in[26];
    float* out = (float*)d_out;

    char* w = (char*)d_ws;
    u16*   XT   = (u16*)(w);                    // [3][16][1024][256]  25165824 B
    u16*   TP   = (u16*)(w + 25165824);         // [3][16][1024][256]  25165824 B (reused as PRE)
    u16*   S    = (u16*)(w + 50331648);         // [3][16][1024][1024] 100663296 B (reused as S1b/S2b/XSb)
    u16*   GXp  = (u16*)(w + 150994944);        // [16][128][1024]     4194304 B
    u16*   GBp  = (u16*)(w + 155189248);        // [16][256][1024]     8388608 B
    u16*   GDp  = (u16*)(w + 163577856);        // [16][256][1024]     8388608 B
    u16*   HX   = (u16*)(w + 171966464);        // [16][1024][128]     4194304 B
    u16*   HS1  = (u16*)(w + 176160768);        // [16][1024][256]     8388608 B
    u16*   HS2  = (u16*)(w + 184549376);        // [16][1024][256]     8388608 B
    u16*   WTP  = (u16*)(w + 192937984);        // 131072 B
    u16*   WG   = (u16*)(w + 193069056);        // 196608 B
    u16*   WW1  = (u16*)(w + 193265664);        // 131072 B
    u16*   WW2  = (u16*)(w + 193396736);        // 131072 B
    u16*   WWX  = (u16*)(w + 193527808);        // 65536 B
    u16*   WOUT = (u16*)(w + 193593344);        // 131072 B
    float* BGf  = (float*)(w + 193724416);      // 1536 B
    float* RS   = (float*)(w + 193725952);      // [3][16][1024] 196608 B
    float* DINV = (float*)(w + 193922560);      // [3][16][1024] 196608 B
    float* BNA  = (float*)(w + 194119168);      // 4096 B
    float* BNP  = (float*)(w + 194123264);      // 4096 B

    u16* S1b = S;                 // [16][1024][256] bf16 (S dead after agg)
    u16* S2b = S + 4194304;
    u16* XSb = S + 8388608;
    u16* PRE = TP;                // TP dead after sym gemm

    // zero RS .. BNA (covers RS, DINV, BNA; atomically accumulated)
    hipMemsetAsync(RS, 0, 397312, stream);

    prep_weights<<<dim3(256), dim3(256), 0, stream>>>(Wt, Wp, Wgx, Wgb, Wgd,
        bgx, bgb, bgd, Wwd, Wwxb, Wwb, Wwxd, Wwx, Wout,
        WTP, WG, WW1, WW2, WWX, WOUT, BGf);
    transpose_cast<<<dim3(32, 8, 48), dim3(32, 8), 0, stream>>>(x, ob, od, XT);

    // t|p = relu(X @ [Wt|Wp]^T)  -> TP
    gemm_bt<128, 256, 2, 4, true, true, false, false><<<dim3(8, 1, 48), 512, 0, stream>>>(
        XT, 262144, 4194304, 256,  WTP, 0, 0, 256,  TP, 262144, 4194304, 256,
        256, nullptr, 0, nullptr, 0);

    // S = sym(t p^T), triangle tiles, fused row sums
    sym_gemm<<<dim3(36, 1, 48), 256, 0, stream>>>(TP, S, RS);
    make_dinv<<<dim3(192), 256, 0, stream>>>(RS, DINV);

    // g convs with fused dinv scaling
    g_conv<<<dim3(1, 8, 48), 256, 0, stream>>>(WG, XT, BGf, DINV, GXp, GBp, GDp);

    // aggregations
    agg_x<<<dim3(8, 1, 16), 256, 0, stream>>>(S, GXp, DINV, HX);
    agg_bd<<<dim3(8, 1, 32), 512, 0, stream>>>(S, GBp, GDp, DINV, HS1, HS2);

    // s1/s2 batched; xs
    gemm_bt<128, 256, 2, 4, false, true, false, false><<<dim3(8, 1, 32), 512, 0, stream>>>(
        HS1, 262144, 4194304, 256,  WW1, 0, 65536, 256,  S1b, 262144, 4194304, 256,
        256, nullptr, 0, nullptr, 0);
    gemm_bt<128, 256, 2, 4, false, true, false, false><<<dim3(8, 1, 16), 512, 0, stream>>>(
        HX, 131072, 0, 128,  WWX, 0, 0, 128,  XSb, 262144, 0, 256,
        128, nullptr, 0, nullptr, 0);

    bn_stats<<<dim3(256, 2), 256, 0, stream>>>(S1b, S2b, BNA);
    bn_finalize<<<1, 256, 0, stream>>>(BNA, g1, be1, g2, be2, BNP);
    combine_kernel<<<dim3(2048), 256, 0, stream>>>(S1b, S2b, XSb, BNP, bwx, PRE);

    // out = Wout @ pre + bout + x
    gemm_bt<128, 256, 2, 4, false, false, true, true><<<dim3(2, 4, 16), 512, 0, stream>>>(
        WOUT, 0, 0, 256,  PRE, 262144, 0, 256,  out, 262144, 0, 1024,
        256, bout, 0, x, 262144);
}

// Round 4
// 185.414 us; speedup vs baseline: 1.3263x; 1.3263x over previous
//
#include <hip/hip_runtime.h>

#define GAS __attribute__((address_space(1)))
#define LAS __attribute__((address_space(3)))

typedef __attribute__((ext_vector_type(8))) short short8;
typedef __attribute__((ext_vector_type(4))) float f32x4;
typedef unsigned short u16;

constexpr int cB = 16, cC = 256, cIC = 128, cN = 1024;

__device__ __forceinline__ u16 f2bf(float v) {
    unsigned u = __builtin_bit_cast(unsigned, v);
    return (u16)((u + 0x7fffu + ((u >> 16) & 1u)) >> 16);
}
__device__ __forceinline__ float bf2f(u16 v) {
    unsigned u = ((unsigned)v) << 16;
    return __builtin_bit_cast(float, u);
}

template<int N> __device__ __forceinline__ void wait_vmcnt() {
    if constexpr (N == 0) asm volatile("s_waitcnt vmcnt(0)" ::: "memory");
    else if constexpr (N == 2) asm volatile("s_waitcnt vmcnt(2)" ::: "memory");
    else if constexpr (N == 3) asm volatile("s_waitcnt vmcnt(3)" ::: "memory");
    else if constexpr (N == 4) asm volatile("s_waitcnt vmcnt(4)" ::: "memory");
    else if constexpr (N == 6) asm volatile("s_waitcnt vmcnt(6)" ::: "memory");
}

// ---------------------------------------------------------------------------
// Double-buffered prefetch GEMM core with LDS XOR-swizzle (2-way max).
// C[m,n] = sum_k A[m,k]*B[n,k]  (both K-major).
// ---------------------------------------------------------------------------
template<int BM, int BN, int WR, int WC>
__device__ __forceinline__ void gemm_core(
    const u16* __restrict__ Ab, int lda,
    const u16* __restrict__ Bb, int ldb, int K,
    u16* lsA, u16* lsB,
    f32x4 (&acc)[BM/(WR*16)][BN/(WC*16)])
{
    constexpr int THREADS = WR * WC * 64;
    constexpr int MR = BM / (WR * 16), NR = BN / (WC * 16);
    constexpr int ACH = (BM * 64) / (THREADS * 16);
    constexpr int BCH = (BN * 64) / (THREADS * 16);
    constexpr int RPC = THREADS / 4;
    constexpr int ISSUES = ACH + BCH;

    const int tid  = threadIdx.x;
    const int lane = tid & 63;
    const int wave = tid >> 6;
    const int wr = wave / WC, wc = wave % WC;
    const int r0 = tid >> 2, slot = tid & 3;

    auto stage = [&](int buf, int kk) {
        const u16* Ak = Ab + kk;
        const u16* Bk = Bb + kk;
        #pragma unroll
        for (int c = 0; c < ACH; c++) {
            int row = c * RPC + r0;
            int sk = (slot ^ ((row >> 1) & 3)) << 3;
            __builtin_amdgcn_global_load_lds((GAS void*)(Ak + (size_t)row * lda + sk),
                (LAS void*)(lsA + buf * (BM * 32) + c * (THREADS * 8) + (wave << 9)), 16, 0, 0);
        }
        #pragma unroll
        for (int c = 0; c < BCH; c++) {
            int row = c * RPC + r0;
            int sk = (slot ^ ((row >> 1) & 3)) << 3;
            __builtin_amdgcn_global_load_lds((GAS void*)(Bk + (size_t)row * ldb + sk),
                (LAS void*)(lsB + buf * (BN * 32) + c * (THREADS * 8) + (wave << 9)), 16, 0, 0);
        }
    };

    stage(0, 0);
    const int nt = K >> 5;
    for (int t = 0; t < nt; t++) {
        const int cur = t & 1;
        if (t + 1 < nt) { stage(cur ^ 1, (t + 1) << 5); wait_vmcnt<ISSUES>(); }
        else            wait_vmcnt<0>();
        __builtin_amdgcn_s_barrier();
        asm volatile("" ::: "memory");

        const u16* la = lsA + cur * (BM * 32);
        const u16* lb = lsB + cur * (BN * 32);
        short8 af[MR], bf[NR];
        #pragma unroll
        for (int m = 0; m < MR; m++) {
            int row = wr * (BM / WR) + (m << 4) + (lane & 15);
            af[m] = *(const short8*)&la[(row << 5) + (((lane >> 4) ^ ((row >> 1) & 3)) << 3)];
        }
        #pragma unroll
        for (int n = 0; n < NR; n++) {
            int row = wc * (BN / WC) + (n << 4) + (lane & 15);
            bf[n] = *(const short8*)&lb[(row << 5) + (((lane >> 4) ^ ((row >> 1) & 3)) << 3)];
        }
        #pragma unroll
        for (int m = 0; m < MR; m++)
            #pragma unroll
            for (int n = 0; n < NR; n++)
                acc[m][n] = __builtin_amdgcn_mfma_f32_16x16x32_bf16(af[m], bf[n], acc[m][n], 0, 0, 0);

        asm volatile("s_waitcnt lgkmcnt(0)" ::: "memory");
        __builtin_amdgcn_sched_barrier(0);
        __builtin_amdgcn_s_barrier();
    }
}

// ---------------------------------------------------------------------------
// Generic GEMM wrapper. z decomposed zlo=z&15, zhi=z>>4.
// RSUM: atomically accumulate fp32 row sums of written values into
// rsum[blockIdx.z * rsStride + row].
// ---------------------------------------------------------------------------
template<int BM, int BN, int WR, int WC, bool RELU, bool OBF16, bool RBIAS, bool RESID, bool RSUM>
__global__ __launch_bounds__(WR*WC*64) void gemm_bt(
    const u16* __restrict__ A, long long sA, long long sA2, int lda,
    const u16* __restrict__ B, long long sB, long long sB2, int ldb,
    void* __restrict__ C, long long sC, long long sC2, int ldc,
    int K,
    const float* __restrict__ bias, int sb2,
    const float* __restrict__ resid, long long sR,
    float* __restrict__ rsum, int rsStride)
{
    __shared__ alignas(16) u16 lsA[2 * BM * 32];
    __shared__ alignas(16) u16 lsB[2 * BN * 32];

    const int lane = threadIdx.x & 63;
    const int wave = threadIdx.x >> 6;
    const int wr = wave / WC, wc = wave % WC;
    const int zlo = blockIdx.z & 15, zhi = blockIdx.z >> 4;

    const u16* Ab = A + zlo * sA + zhi * sA2 + (size_t)(blockIdx.x * BM) * lda;
    const u16* Bb = B + zlo * sB + zhi * sB2 + (size_t)(blockIdx.y * BN) * ldb;

    f32x4 acc[BM/(WR*16)][BN/(WC*16)] = {};
    gemm_core<BM, BN, WR, WC>(Ab, lda, Bb, ldb, K, lsA, lsB, acc);

    const int rowb = blockIdx.x * BM + wr * (BM / WR) + ((lane >> 4) << 2);
    const int colb = blockIdx.y * BN + wc * (BN / WC) + (lane & 15);
    const long long cbase = zlo * sC + zhi * sC2;
    float rp[BM/(WR*16)][4] = {};
    #pragma unroll
    for (int m = 0; m < BM/(WR*16); m++) {
        #pragma unroll
        for (int n = 0; n < BN/(WC*16); n++) {
            #pragma unroll
            for (int r = 0; r < 4; r++) {
                int row = rowb + m * 16 + r;
                int col = colb + n * 16;
                float v = acc[m][n][r];
                if (RBIAS) v += bias[zhi * sb2 + row];
                if (RESID) v += resid[zlo * sR + (size_t)row * ldc + col];
                if (RELU)  v = fmaxf(v, 0.0f);
                if (RSUM)  rp[m][r] += v;
                if (OBF16) ((u16*)C)[cbase + (size_t)row * ldc + col] = f2bf(v);
                else       ((float*)C)[cbase + (size_t)row * ldc + col] = v;
            }
        }
    }
    if (RSUM) {
        #pragma unroll
        for (int m = 0; m < BM/(WR*16); m++) {
            #pragma unroll
            for (int r = 0; r < 4; r++) {
                float v = rp[m][r];
                v += __shfl_xor(v, 1, 64);
                v += __shfl_xor(v, 2, 64);
                v += __shfl_xor(v, 4, 64);
                v += __shfl_xor(v, 8, 64);
                if ((lane & 15) == 0)
                    atomicAdd(&rsum[(size_t)blockIdx.z * rsStride + rowb + m * 16 + r], v);
            }
        }
    }
}

// ---------------------------------------------------------------------------
// Inner factor GEMM: M[c][j] = sum_n TPt[z][c][n] * Gd[j][n], written with
// row flip (c ^ 128) so downstream reads pair T-rows with P-sums.
// z = which*16+b; which 0: x (NI=128), 1: b, 2: d (NI=256).
// ---------------------------------------------------------------------------
__global__ __launch_bounds__(256) void inner_gemm(
    const u16* __restrict__ TPt, const u16* __restrict__ GXp,
    const u16* __restrict__ GBp, const u16* __restrict__ GDp,
    u16* __restrict__ MX, u16* __restrict__ MB, u16* __restrict__ MD)
{
    __shared__ alignas(16) u16 lsA[2 * 128 * 32];
    __shared__ alignas(16) u16 lsB[2 * 128 * 32];

    const int z = blockIdx.z, which = z >> 4, b = z & 15;
    if (which == 0 && blockIdx.y != 0) return;
    const u16* Gp = (which == 0) ? GXp : (which == 1) ? GBp : GDp;
    u16* M = (which == 0) ? MX : (which == 1) ? MB : MD;
    const int ldc = (which == 0) ? 128 : 256;
    const long long sB = (which == 0) ? 131072 : 262144;

    const u16* Ab = TPt + (size_t)z * 262144 + (size_t)(blockIdx.x * 128) * 1024;
    const u16* Bb = Gp + (size_t)b * sB + (size_t)(blockIdx.y * 128) * 1024;

    f32x4 acc[4][4] = {};
    gemm_core<128, 128, 2, 2>(Ab, 1024, Bb, 1024, 1024, lsA, lsB, acc);

    const int lane = threadIdx.x & 63;
    const int wave = threadIdx.x >> 6;
    const int wr = wave >> 1, wc = wave & 1;
    const int rowb = blockIdx.x * 128 + (wr << 6) + ((lane >> 4) << 2);
    const int colb = blockIdx.y * 128 + (wc << 6) + (lane & 15);
    u16* Cb = M + (size_t)b * (256 * ldc);
    #pragma unroll
    for (int m = 0; m < 4; m++)
        #pragma unroll
        for (int n = 0; n < 4; n++)
            #pragma unroll
            for (int r = 0; r < 4; r++) {
                int row = (rowb + m * 16 + r) ^ 128;
                int col = colb + n * 16;
                Cb[(size_t)row * ldc + col] = f2bf(acc[m][n][r]);
            }
}

// ---------------------------------------------------------------------------
// Fold GEMM: FF[q][b][o][c] = sum_j WF[q][o][j] * Msel[b][c][coff+j]
// q: 0=dd(MD,0) 1=bx(MB,128) 2=bb(MB,0) 3=dx(MD,128) 4=xx(MX,0); K=128.
// ---------------------------------------------------------------------------
__global__ __launch_bounds__(512) void fold_gemm(
    const u16* __restrict__ WF, const u16* __restrict__ MX,
    const u16* __restrict__ MB, const u16* __restrict__ MD,
    u16* __restrict__ FF)
{
    __shared__ alignas(16) u16 lsA[2 * 128 * 32];
    __shared__ alignas(16) u16 lsB[2 * 256 * 32];

    const int z = blockIdx.z, q = z >> 4, b = z & 15;
    const u16* Mp = (q == 4) ? MX : (q == 1 || q == 2) ? MB : MD;
    const int coff = (q == 1 || q == 3) ? 128 : 0;
    const int ldb  = (q == 4) ? 128 : 256;

    const u16* Ab = WF + q * 32768 + (size_t)(blockIdx.x * 128) * 128;
    const u16* Bb = Mp + (size_t)b * (256 * ldb) + coff;

    f32x4 acc[4][4] = {};
    gemm_core<128, 256, 2, 4>(Ab, 128, Bb, ldb, 128, lsA, lsB, acc);

    const int lane = threadIdx.x & 63;
    const int wave = threadIdx.x >> 6;
    const int wr = wave >> 2, wc = wave & 3;
    const int rowb = blockIdx.x * 128 + (wr << 6) + ((lane >> 4) << 2);
    const int colb = (wc << 6) + (lane & 15);
    u16* Cb = FF + (size_t)q * 1048576 + (size_t)b * 65536;
    #pragma unroll
    for (int m = 0; m < 4; m++)
        #pragma unroll
        for (int n = 0; n < 4; n++)
            #pragma unroll
            for (int r = 0; r < 4; r++)
                Cb[(size_t)(rowb + m * 16 + r) * 256 + colb + n * 16] = f2bf(acc[m][n][r]);
}

// ---------------------------------------------------------------------------
// Outer dual GEMM: out = dv1 o (TP_a1 @ F1^T) [+ dv2 o (TP_a2 @ F2^T)].
// zhi 0: s1 = dvd o (TP_d F_dd) + dvb o (TP_b F_bx)
// zhi 1: s2 = dvb o (TP_b F_bb) + dvd o (TP_d F_dx)
// zhi 2: xs = dvx o (TP_x F_xx)
// ---------------------------------------------------------------------------
__global__ __launch_bounds__(512) void outer_gemm(
    const u16* __restrict__ TP, const u16* __restrict__ FF,
    const float* __restrict__ DINV,
    u16* __restrict__ S1b, u16* __restrict__ S2b, u16* __restrict__ XSb)
{
    __shared__ alignas(16) u16 lsA[2 * 128 * 32];
    __shared__ alignas(16) u16 lsB[2 * 256 * 32];

    const int z = blockIdx.z, zhi = z >> 4, b = z & 15;
    const int sa1[3] = {2, 1, 0}, if1[3] = {0, 2, 4};
    const int sa2[3] = {1, 2, 0}, if2[3] = {1, 3, 0};

    const int lane = threadIdx.x & 63;
    const int wave = threadIdx.x >> 6;
    const int wr = wave >> 2, wc = wave & 3;
    const int rowb = blockIdx.x * 128 + (wr << 5) + ((lane >> 4) << 2);
    // note: WR=2 over BM=128 -> per-wave row span 64; recompute properly below
    const int rowb2 = blockIdx.x * 128 + wr * 64 + ((lane >> 4) << 2);
    (void)rowb;
    const int colb = (wc << 6) + (lane & 15);

    const u16* A1 = TP + (size_t)(sa1[zhi] * 16 + b) * 262144 + (size_t)(blockIdx.x * 128) * 256;
    const u16* B1 = FF + (size_t)if1[zhi] * 1048576 + (size_t)b * 65536;
    const float* dv1 = DINV + sa1[zhi] * 16384 + (b << 10);

    f32x4 acc[4][4] = {};
    gemm_core<128, 256, 2, 4>(A1, 256, B1, 256, 256, lsA, lsB, acc);

    f32x4 keep[4][4];
    #pragma unroll
    for (int m = 0; m < 4; m++) {
        f32x4 dva = *(const f32x4*)&dv1[rowb2 + m * 16];
        #pragma unroll
        for (int n = 0; n < 4; n++) keep[m][n] = acc[m][n] * dva;
    }

    if (zhi != 2) {
        const u16* A2 = TP + (size_t)(sa2[zhi] * 16 + b) * 262144 + (size_t)(blockIdx.x * 128) * 256;
        const u16* B2 = FF + (size_t)if2[zhi] * 1048576 + (size_t)b * 65536;
        const float* dv2 = DINV + sa2[zhi] * 16384 + (b << 10);
        #pragma unroll
        for (int m = 0; m < 4; m++)
            #pragma unroll
            for (int n = 0; n < 4; n++) acc[m][n] = f32x4{0.f, 0.f, 0.f, 0.f};
        gemm_core<128, 256, 2, 4>(A2, 256, B2, 256, 256, lsA, lsB, acc);
        #pragma unroll
        for (int m = 0; m < 4; m++) {
            f32x4 dvb4 = *(const f32x4*)&dv2[rowb2 + m * 16];
            #pragma unroll
            for (int n = 0; n < 4; n++) keep[m][n] = keep[m][n] + acc[m][n] * dvb4;
        }
    }

    u16* Cb = ((zhi == 0) ? S1b : (zhi == 1) ? S2b : XSb) + (size_t)b * 262144;
    #pragma unroll
    for (int m = 0; m < 4; m++)
        #pragma unroll
        for (int n = 0; n < 4; n++)
            #pragma unroll
            for (int r = 0; r < 4; r++)
                Cb[(size_t)(rowb2 + m * 16 + r) * 256 + colb + n * 16] = f2bf(keep[m][n][r]);
}

// ---------------------------------------------------------------------------
// g-conv with fused dinv scaling (unchanged from r3).
// ---------------------------------------------------------------------------
__global__ __launch_bounds__(256) void g_conv(
    const u16* __restrict__ WG, const u16* __restrict__ XT,
    const float* __restrict__ BG, const float* __restrict__ DINV,
    u16* __restrict__ GXp, u16* __restrict__ GBp, u16* __restrict__ GDp)
{
    __shared__ alignas(16) u16 lsA[2 * 128 * 32];
    __shared__ alignas(16) u16 lsB[2 * 128 * 32];

    const int zlo = blockIdx.z & 15, zhi = blockIdx.z >> 4;
    const u16* Ab = WG + zhi * 32768;
    const u16* Bb = XT + (size_t)zhi * 4194304 + (size_t)zlo * 262144 + (size_t)(blockIdx.y * 128) * 256;

    f32x4 acc[4][4] = {};
    gemm_core<128, 128, 2, 2>(Ab, 256, Bb, 256, 256, lsA, lsB, acc);

    const int lane = threadIdx.x & 63;
    const int wave = threadIdx.x >> 6;
    const int wr = wave >> 1, wc = wave & 1;
    const int rowb = (wr << 6) + ((lane >> 4) << 2);
    const int colb = blockIdx.y * 128 + (wc << 6) + (lane & 15);
    const float* dvx = DINV + (zlo << 10);
    const float* dvb = DINV + 16384 + (zlo << 10);
    const float* dvd = DINV + 32768 + (zlo << 10);

    #pragma unroll
    for (int m = 0; m < 4; m++) {
        #pragma unroll
        for (int n = 0; n < 4; n++) {
            #pragma unroll
            for (int r = 0; r < 4; r++) {
                int row = rowb + m * 16 + r;
                int col = colb + n * 16;
                float v = acc[m][n][r] + BG[zhi * 128 + row];
                size_t i128 = (size_t)zlo * 131072 + ((size_t)row << 10) + col;
                size_t i256 = (size_t)zlo * 262144 + ((size_t)row << 10) + col;
                size_t i256h = (size_t)zlo * 262144 + ((size_t)(row + 128) << 10) + col;
                if (zhi == 0) {
                    GXp[i128]  = f2bf(v * dvx[col]);
                    GBp[i256h] = f2bf(v * dvb[col]);
                    GDp[i256h] = f2bf(v * dvd[col]);
                } else if (zhi == 1) {
                    GBp[i256] = f2bf(v * dvb[col]);
                } else {
                    GDp[i256] = f2bf(v * dvd[col]);
                }
            }
        }
    }
}

// ---------------------------------------------------------------------------
__global__ void transpose_cast(const float* __restrict__ x, const float* __restrict__ ob,
                               const float* __restrict__ od, u16* __restrict__ xt)
{
    __shared__ float t[32][33];
    int z = blockIdx.z, which = z >> 4, b = z & 15;
    const float* src = (which == 0) ? x : (which == 1) ? ob : od;
    const float* s = src + (size_t)b * cC * cN;
    u16* dst = xt + (size_t)which * (cB * cN * cC) + (size_t)b * (cN * cC);
    int n0 = blockIdx.x << 5, c0 = blockIdx.y << 5;
    int tx = threadIdx.x, ty = threadIdx.y;
    #pragma unroll
    for (int i = 0; i < 4; i++) { int r = ty + (i << 3); t[r][tx] = s[(size_t)(c0 + r) * cN + n0 + tx]; }
    __syncthreads();
    #pragma unroll
    for (int i = 0; i < 4; i++) { int r = ty + (i << 3); dst[(size_t)(n0 + r) * cC + c0 + tx] = f2bf(t[tx][r]); }
}

__global__ void prep_weights(const float* Wt, const float* Wp,
                             const float* Wgx, const float* Wgb, const float* Wgd,
                             const float* bgx, const float* bgb, const float* bgd,
                             const float* Wwd, const float* Wwxb, const float* Wwb,
                             const float* Wwxd, const float* Wwx, const float* Wout,
                             u16* wtp, u16* wg, u16* wf, u16* wout, float* bg)
{
    int t = blockIdx.x * 256 + threadIdx.x;   // 65536
    wtp[t]  = f2bf(t < 32768 ? Wt[t] : Wp[t - 32768]);
    wout[t] = f2bf(Wout[t]);
    if (t < 32768) {
        wg[t] = f2bf(Wgx[t]); wg[32768 + t] = f2bf(Wgb[t]); wg[65536 + t] = f2bf(Wgd[t]);
        wf[t]           = f2bf(0.5f * Wwd[t]);
        wf[32768 + t]   = f2bf(0.5f * Wwxb[t]);
        wf[65536 + t]   = f2bf(0.5f * Wwb[t]);
        wf[98304 + t]   = f2bf(0.5f * Wwxd[t]);
        wf[131072 + t]  = f2bf(0.5f * Wwx[t]);
    }
    if (t < 384) bg[t] = (t < 128) ? bgx[t] : (t < 256) ? bgb[t - 128] : bgd[t - 256];
}

// ---------------------------------------------------------------------------
// Degree matvec: DINV[z][n] += sum over a 64-chunk of c of TPt[z][c][n]*ws[c],
// ws[c] = 0.5 * CS[z][c^128]. Finalized to rsqrt by finish_dinv.
// ---------------------------------------------------------------------------
__global__ void dinv_partial(const u16* __restrict__ TPt, const float* __restrict__ CS,
                             float* __restrict__ DINV)
{
    int z = blockIdx.y;
    int cq = blockIdx.z;                       // c-quarter 0..3
    int n = blockIdx.x * 256 + threadIdx.x;
    __shared__ float ws[64];
    if (threadIdx.x < 64) {
        int c = cq * 64 + threadIdx.x;
        ws[threadIdx.x] = 0.5f * CS[z * 256 + (c ^ 128)];
    }
    __syncthreads();
    const u16* base = TPt + (size_t)z * 262144 + (size_t)(cq * 64) * 1024 + n;
    float d = 0;
    #pragma unroll 16
    for (int c = 0; c < 64; c++) d += bf2f(base[(size_t)c << 10]) * ws[c];
    atomicAdd(&DINV[(z << 10) + n], d);
}

__global__ void finish_dinv(float* __restrict__ DINV)
{
    int i = blockIdx.x * 256 + threadIdx.x;   // 49152
    float d = DINV[i];
    DINV[i] = (d != 0.0f) ? rsqrtf(d) : 0.0f;
}

// ---------------------------------------------------------------------------
__global__ void bn_stats(const u16* __restrict__ s1, const u16* __restrict__ s2,
                         float* __restrict__ acc)
{
    int c = threadIdx.x;
    const u16* s = blockIdx.y ? s2 : s1;
    float* a = acc + blockIdx.y * 512;
    size_t r0 = (size_t)blockIdx.x * 64;
    float sum = 0, sq = 0;
    for (int r = 0; r < 64; r++) { float v = bf2f(s[(r0 + r) * 256 + c]); sum += v; sq += v * v; }
    atomicAdd(&a[c], sum);
    atomicAdd(&a[256 + c], sq);
}

__global__ void bn_finalize(const float* __restrict__ acc,
                            const float* g1, const float* b1,
                            const float* g2, const float* b2,
                            float* __restrict__ p)
{
    int c = threadIdx.x;
    const float inv = 1.0f / 16384.0f;
    for (int k = 0; k < 2; k++) {
        float mean = acc[k * 512 + c] * inv;
        float var  = acc[k * 512 + 256 + c] * inv - mean * mean;
        const float* g = k ? g2 : g1;
        const float* be = k ? b2 : b1;
        float sc = g[c] * rsqrtf(var + 1e-5f);
        p[k * 512 + c] = sc;
        p[k * 512 + 256 + c] = be[c] - mean * sc;
    }
}

__global__ void combine_kernel(const u16* __restrict__ s1, const u16* __restrict__ s2,
                               const u16* __restrict__ xs, const float* __restrict__ p,
                               const float* __restrict__ bwx, u16* __restrict__ pre)
{
    size_t t = (size_t)blockIdx.x * 256 + threadIdx.x;   // 524288
    size_t base = t << 3;
    int c0 = (int)(base & 255);
    short8 a = *(const short8*)(s1 + base);
    short8 b = *(const short8*)(s2 + base);
    short8 cx = *(const short8*)(xs + base);
    short8 o;
    #pragma unroll
    for (int j = 0; j < 8; j++) {
        int c = c0 + j;
        float v = p[c] * bf2f((u16)a[j]) + p[256 + c]
                + p[512 + c] * bf2f((u16)b[j]) + p[768 + c]
                + bf2f((u16)cx[j]) + bwx[c];
        o[j] = (short)f2bf(v);
    }
    *(short8*)(pre + base) = o;
}

// ---------------------------------------------------------------------------
extern "C" void kernel_launch(void* const* d_in, const int* in_sizes, int n_in,
                              void* d_out, int out_size, void* d_ws, size_t ws_size,
                              hipStream_t stream)
{
    const float* x    = (const float*)d_in[0];
    const float* ob   = (const float*)d_in[1];
    const float* od   = (const float*)d_in[2];
    const float* Wt   = (const float*)d_in[3];
    const float* Wp   = (const float*)d_in[4];
    const float* Wgx  = (const float*)d_in[5];
    const float* bgx  = (const float*)d_in[6];
    const float* Wgb  = (const float*)d_in[7];
    const float* bgb  = (const float*)d_in[8];
    const float* Wgd  = (const float*)d_in[9];
    const float* bgd  = (const float*)d_in[10];
    const float* Wwx  = (const float*)d_in[11];
    const float* bwx  = (const float*)d_in[12];
    const float* Wwb  = (const float*)d_in[13];
    const float* Wwd  = (const float*)d_in[15];
    const float* Wwxb = (const float*)d_in[17];
    const float* Wwxd = (const float*)d_in[19];
    const float* g1   = (const float*)d_in[21];
    const float* be1  = (const float*)d_in[22];
    const float* g2   = (const float*)d_in[23];
    const float* be2  = (const float*)d_in[24];
    const float* Wout = (const float*)d_in[25];
    const float* bout = (const float*)d_in[26];
    float* out = (float*)d_out;

    char* w = (char*)d_ws;
    u16*   XT   = (u16*)(w);                    // [3][16][1024][256]  25165824 B
    u16*   TP   = (u16*)(w + 25165824);         // [3][16][1024][256]  25165824 B
    u16*   TPt  = (u16*)(w + 50331648);         // [3][16][256][1024]  25165824 B (reused as PRE)
    u16*   GXp  = (u16*)(w + 75497472);         // [16][128][1024]     4194304 B
    u16*   GBp  = (u16*)(w + 79691776);         // [16][256][1024]     8388608 B
    u16*   GDp  = (u16*)(w + 88080384);         // [16][256][1024]     8388608 B
    u16*   MX   = (u16*)(w + 96468992);         // [16][256][128]      1048576 B
    u16*   MB   = (u16*)(w + 97517568);         // [16][256][256]      2097152 B
    u16*   MD   = (u16*)(w + 99614720);         // [16][256][256]      2097152 B
    u16*   FF   = (u16*)(w + 101711872);        // [5][16][256][256]   10485760 B
    u16*   S1b  = (u16*)(w + 112197632);        // [16][1024][256]     8388608 B
    u16*   S2b  = (u16*)(w + 120586240);        // 8388608 B
    u16*   XSb  = (u16*)(w + 128974848);        // 8388608 B
    u16*   WTP  = (u16*)(w + 137363456);        // 131072 B
    u16*   WG   = (u16*)(w + 137494528);        // 196608 B
    u16*   WF   = (u16*)(w + 137691136);        // 327680 B
    u16*   WOUT = (u16*)(w + 138018816);        // 131072 B
    float* BGf  = (float*)(w + 138149888);      // 1536 B (pad)
    float* CS   = (float*)(w + 138151936);      // [48][256] 49152 B
    float* BNA  = (float*)(w + 138201088);      // 4096 B
    float* DINV = (float*)(w + 138205184);      // [3][16][1024] 196608 B
    float* BNP  = (float*)(w + 138401792);      // 4096 B

    u16* PRE = TPt;   // TPt dead after inner+dinv; combine writes PRE later

    // zero CS + BNA + DINV (all atomically accumulated per launch)
    hipMemsetAsync(CS, 0, 249856, stream);

    prep_weights<<<dim3(256), dim3(256), 0, stream>>>(Wt, Wp, Wgx, Wgb, Wgd,
        bgx, bgb, bgd, Wwd, Wwxb, Wwb, Wwxd, Wwx, Wout,
        WTP, WG, WF, WOUT, BGf);
    transpose_cast<<<dim3(32, 8, 48), dim3(32, 8), 0, stream>>>(x, ob, od, XT);

    // TP = relu(XT @ WTP^T)  [3·16][1024][256]
    gemm_bt<128, 256, 2, 4, true, true, false, false, false><<<dim3(8, 1, 48), 512, 0, stream>>>(
        XT, 262144, 4194304, 256,  WTP, 0, 0, 256,  TP, 262144, 4194304, 256,
        256, nullptr, 0, nullptr, 0, nullptr, 0);

    // TPt = relu(WTP @ XT^T) [3·16][256][1024], fused column-sums -> CS
    gemm_bt<128, 256, 2, 4, true, true, false, false, true><<<dim3(2, 4, 48), 512, 0, stream>>>(
        WTP, 0, 0, 256,  XT, 262144, 4194304, 256,  TPt, 262144, 4194304, 1024,
        256, nullptr, 0, nullptr, 0, CS, 256);

    // degree -> dinv
    dinv_partial<<<dim3(4, 48, 4), 256, 0, stream>>>(TPt, CS, DINV);
    finish_dinv<<<dim3(192), 256, 0, stream>>>(DINV);

    // g convs with fused dinv scaling
    g_conv<<<dim3(1, 8, 48), 256, 0, stream>>>(WG, XT, BGf, DINV, GXp, GBp, GDp);

    // inner factors M = TPt @ Gd^T (K=1024), row-flipped
    inner_gemm<<<dim3(2, 2, 48), 256, 0, stream>>>(TPt, GXp, GBp, GDp, MX, MB, MD);

    // folds F = 0.5*W @ M-half (K=128)
    fold_gemm<<<dim3(2, 1, 80), 512, 0, stream>>>(WF, MX, MB, MD, FF);

    // outers: s1/s2/xs with per-row dinv scaling
    outer_gemm<<<dim3(8, 1, 48), 512, 0, stream>>>(TP, FF, DINV, S1b, S2b, XSb);

    bn_stats<<<dim3(256, 2), 256, 0, stream>>>(S1b, S2b, BNA);
    bn_finalize<<<1, 256, 0, stream>>>(BNA, g1, be1, g2, be2, BNP);
    combine_kernel<<<dim3(2048), 256, 0, stream>>>(S1b, S2b, XSb, BNP, bwx, PRE);

    // out = Wout @ pre + bout + x
    gemm_bt<128, 256, 2, 4, false, false, true, true, false><<<dim3(2, 4, 16), 512, 0, stream>>>(
        WOUT, 0, 0, 256,  PRE, 262144, 0, 256,  out, 262144, 0, 1024,
        256, bout, 0, x, 262144, nullptr, 0);
}

// Round 5
// 166.921 us; speedup vs baseline: 1.4733x; 1.1108x over previous
//
#include <hip/hip_runtime.h>

#define GAS __attribute__((address_space(1)))
#define LAS __attribute__((address_space(3)))

typedef __attribute__((ext_vector_type(8))) short short8;
typedef __attribute__((ext_vector_type(4))) float f32x4;
typedef unsigned short u16;

constexpr int cB = 16, cC = 256, cIC = 128, cN = 1024;

__device__ __forceinline__ u16 f2bf(float v) {
    unsigned u = __builtin_bit_cast(unsigned, v);
    return (u16)((u + 0x7fffu + ((u >> 16) & 1u)) >> 16);
}
__device__ __forceinline__ float bf2f(u16 v) {
    unsigned u = ((unsigned)v) << 16;
    return __builtin_bit_cast(float, u);
}
__device__ __forceinline__ float rsz(float d) {
    return (d != 0.0f) ? rsqrtf(d) : 0.0f;
}

template<int N> __device__ __forceinline__ void wait_vmcnt() {
    if constexpr (N == 0) asm volatile("s_waitcnt vmcnt(0)" ::: "memory");
    else if constexpr (N == 1) asm volatile("s_waitcnt vmcnt(1)" ::: "memory");
    else if constexpr (N == 2) asm volatile("s_waitcnt vmcnt(2)" ::: "memory");
    else if constexpr (N == 3) asm volatile("s_waitcnt vmcnt(3)" ::: "memory");
    else if constexpr (N == 4) asm volatile("s_waitcnt vmcnt(4)" ::: "memory");
    else if constexpr (N == 5) asm volatile("s_waitcnt vmcnt(5)" ::: "memory");
    else if constexpr (N == 6) asm volatile("s_waitcnt vmcnt(6)" ::: "memory");
}

// ---------------------------------------------------------------------------
// Double-buffered prefetch GEMM core with LDS XOR-swizzle (2-way max).
// C[m,n] = sum_k A[m,k]*B[n,k]  (both K-major).
// Dual-A: for kk >= ksplit reads Ab2 + (kk - ksplit) (K-concat of two mats).
// ---------------------------------------------------------------------------
template<int BM, int BN, int WR, int WC>
__device__ __forceinline__ void gemm_core(
    const u16* __restrict__ Ab, const u16* __restrict__ Ab2, int ksplit, int lda,
    const u16* __restrict__ Bb, int ldb, int K,
    u16* lsA, u16* lsB,
    f32x4 (&acc)[BM/(WR*16)][BN/(WC*16)])
{
    constexpr int THREADS = WR * WC * 64;
    constexpr int MR = BM / (WR * 16), NR = BN / (WC * 16);
    constexpr int ACH = (BM * 64) / (THREADS * 16);
    constexpr int BCH = (BN * 64) / (THREADS * 16);
    constexpr int RPC = THREADS / 4;
    constexpr int ISSUES = ACH + BCH;

    const int tid  = threadIdx.x;
    const int lane = tid & 63;
    const int wave = tid >> 6;
    const int wr = wave / WC, wc = wave % WC;
    const int r0 = tid >> 2, slot = tid & 3;

    auto stage = [&](int buf, int kk) {
        const u16* Ak = (Ab2 != nullptr && kk >= ksplit) ? (Ab2 + (kk - ksplit)) : (Ab + kk);
        const u16* Bk = Bb + kk;
        #pragma unroll
        for (int c = 0; c < ACH; c++) {
            int row = c * RPC + r0;
            int sk = (slot ^ ((row >> 1) & 3)) << 3;
            __builtin_amdgcn_global_load_lds((GAS void*)(Ak + (size_t)row * lda + sk),
                (LAS void*)(lsA + buf * (BM * 32) + c * (THREADS * 8) + (wave << 9)), 16, 0, 0);
        }
        #pragma unroll
        for (int c = 0; c < BCH; c++) {
            int row = c * RPC + r0;
            int sk = (slot ^ ((row >> 1) & 3)) << 3;
            __builtin_amdgcn_global_load_lds((GAS void*)(Bk + (size_t)row * ldb + sk),
                (LAS void*)(lsB + buf * (BN * 32) + c * (THREADS * 8) + (wave << 9)), 16, 0, 0);
        }
    };

    stage(0, 0);
    const int nt = K >> 5;
    for (int t = 0; t < nt; t++) {
        const int cur = t & 1;
        if (t + 1 < nt) { stage(cur ^ 1, (t + 1) << 5); wait_vmcnt<ISSUES>(); }
        else            wait_vmcnt<0>();
        __builtin_amdgcn_s_barrier();
        asm volatile("" ::: "memory");

        const u16* la = lsA + cur * (BM * 32);
        const u16* lb = lsB + cur * (BN * 32);
        short8 af[MR], bf[NR];
        #pragma unroll
        for (int m = 0; m < MR; m++) {
            int row = wr * (BM / WR) + (m << 4) + (lane & 15);
            af[m] = *(const short8*)&la[(row << 5) + (((lane >> 4) ^ ((row >> 1) & 3)) << 3)];
        }
        #pragma unroll
        for (int n = 0; n < NR; n++) {
            int row = wc * (BN / WC) + (n << 4) + (lane & 15);
            bf[n] = *(const short8*)&lb[(row << 5) + (((lane >> 4) ^ ((row >> 1) & 3)) << 3)];
        }
        #pragma unroll
        for (int m = 0; m < MR; m++)
            #pragma unroll
            for (int n = 0; n < NR; n++)
                acc[m][n] = __builtin_amdgcn_mfma_f32_16x16x32_bf16(af[m], bf[n], acc[m][n], 0, 0, 0);

        asm volatile("s_waitcnt lgkmcnt(0)" ::: "memory");
        __builtin_amdgcn_sched_barrier(0);
        __builtin_amdgcn_s_barrier();
    }
}

// ---------------------------------------------------------------------------
// Generic GEMM wrapper. z decomposed zlo=z&15, zhi=z>>4.
// RSUM: fp32 row-sum atomics into rsum[z * rsStride + row].
// ---------------------------------------------------------------------------
template<int BM, int BN, int WR, int WC, bool RELU, bool OBF16, bool RBIAS, bool RESID, bool RSUM>
__global__ __launch_bounds__(WR*WC*64) void gemm_bt(
    const u16* __restrict__ A, long long sA, long long sA2, int lda,
    const u16* __restrict__ B, long long sB, long long sB2, int ldb,
    void* __restrict__ C, long long sC, long long sC2, int ldc,
    int K,
    const float* __restrict__ bias, int sb2,
    const float* __restrict__ resid, long long sR,
    float* __restrict__ rsum, int rsStride)
{
    __shared__ alignas(16) u16 lsA[2 * BM * 32];
    __shared__ alignas(16) u16 lsB[2 * BN * 32];

    const int lane = threadIdx.x & 63;
    const int wave = threadIdx.x >> 6;
    const int wr = wave / WC, wc = wave % WC;
    const int zlo = blockIdx.z & 15, zhi = blockIdx.z >> 4;

    const u16* Ab = A + zlo * sA + zhi * sA2 + (size_t)(blockIdx.x * BM) * lda;
    const u16* Bb = B + zlo * sB + zhi * sB2 + (size_t)(blockIdx.y * BN) * ldb;

    f32x4 acc[BM/(WR*16)][BN/(WC*16)] = {};
    gemm_core<BM, BN, WR, WC>(Ab, nullptr, K, lda, Bb, ldb, K, lsA, lsB, acc);

    const int rowb = blockIdx.x * BM + wr * (BM / WR) + ((lane >> 4) << 2);
    const int colb = blockIdx.y * BN + wc * (BN / WC) + (lane & 15);
    const long long cbase = zlo * sC + zhi * sC2;
    float rp[BM/(WR*16)][4] = {};
    #pragma unroll
    for (int m = 0; m < BM/(WR*16); m++) {
        #pragma unroll
        for (int n = 0; n < BN/(WC*16); n++) {
            #pragma unroll
            for (int r = 0; r < 4; r++) {
                int row = rowb + m * 16 + r;
                int col = colb + n * 16;
                float v = acc[m][n][r];
                if (RBIAS) v += bias[zhi * sb2 + row];
                if (RESID) v += resid[zlo * sR + (size_t)row * ldc + col];
                if (RELU)  v = fmaxf(v, 0.0f);
                if (RSUM)  rp[m][r] += v;
                if (OBF16) ((u16*)C)[cbase + (size_t)row * ldc + col] = f2bf(v);
                else       ((float*)C)[cbase + (size_t)row * ldc + col] = v;
            }
        }
    }
    if (RSUM) {
        #pragma unroll
        for (int m = 0; m < BM/(WR*16); m++) {
            #pragma unroll
            for (int r = 0; r < 4; r++) {
                float v = rp[m][r];
                v += __shfl_xor(v, 1, 64);
                v += __shfl_xor(v, 2, 64);
                v += __shfl_xor(v, 4, 64);
                v += __shfl_xor(v, 8, 64);
                if ((lane & 15) == 0)
                    atomicAdd(&rsum[(size_t)blockIdx.z * rsStride + rowb + m * 16 + r], v);
            }
        }
    }
}

// ---------------------------------------------------------------------------
// phase2: one dispatch, two sub-ops sharing tile shape <128,256,2,4>, K=256.
//   id<384 : TPS = dv[n] o relu(XT @ WTP^T)      (A=XT rows n, B=WTP)
//   id>=384: G   = dv[col] o (WG @ XT^T + bg)    (A=WG rows ic, B=XT rows n)
// ---------------------------------------------------------------------------
__global__ __launch_bounds__(512) void phase2(
    const u16* __restrict__ XT, const u16* __restrict__ WTP, const u16* __restrict__ WG,
    const float* __restrict__ BG, const float* __restrict__ DINV,
    u16* __restrict__ TPS, u16* __restrict__ GXp, u16* __restrict__ GBp, u16* __restrict__ GDp)
{
    __shared__ alignas(16) u16 lsA[2 * 128 * 32];
    __shared__ alignas(16) u16 lsB[2 * 256 * 32];

    const int id = blockIdx.x;
    const bool tp_path = (id < 384);
    int xb, yb, zs;
    if (tp_path) { xb = id & 7; zs = id >> 3; yb = 0; }
    else         { int g = id - 384; yb = g & 3; zs = g >> 2; xb = 0; }
    const int stream = zs >> 4, b = zs & 15;

    const u16* Ab;
    const u16* Bb;
    if (tp_path) {
        Ab = XT + (size_t)zs * 262144 + (size_t)(xb * 128) * 256;
        Bb = WTP;
    } else {
        Ab = WG + stream * 32768;
        Bb = XT + (size_t)zs * 262144 + (size_t)(yb * 256) * 256;
    }

    f32x4 acc[4][4] = {};
    gemm_core<128, 256, 2, 4>(Ab, nullptr, 256, 256, Bb, 256, 256, lsA, lsB, acc);

    const int lane = threadIdx.x & 63;
    const int wave = threadIdx.x >> 6;
    const int wr = wave >> 2, wc = wave & 3;

    if (tp_path) {
        const int rowb = xb * 128 + wr * 64 + ((lane >> 4) << 2);
        const int colb = wc * 64 + (lane & 15);
        const float* dvr = DINV + stream * 16384 + (b << 10);
        u16* Cb = TPS + (size_t)zs * 262144;
        #pragma unroll
        for (int m = 0; m < 4; m++) {
            #pragma unroll
            for (int r = 0; r < 4; r++) {
                int row = rowb + m * 16 + r;
                float s = rsz(dvr[row]);
                #pragma unroll
                for (int n = 0; n < 4; n++)
                    Cb[(size_t)row * 256 + colb + n * 16] = f2bf(fmaxf(acc[m][n][r], 0.0f) * s);
            }
        }
    } else {
        const int rowb = wr * 64 + ((lane >> 4) << 2);
        const int colb = yb * 256 + wc * 64 + (lane & 15);
        const float* dvx = DINV + (b << 10);
        const float* dvb = DINV + 16384 + (b << 10);
        const float* dvd = DINV + 32768 + (b << 10);
        float sx[4], sb_[4], sd[4];
        #pragma unroll
        for (int n = 0; n < 4; n++) {
            int col = colb + n * 16;
            if (stream == 0) { sx[n] = rsz(dvx[col]); sb_[n] = rsz(dvb[col]); sd[n] = rsz(dvd[col]); }
            else if (stream == 1) sb_[n] = rsz(dvb[col]);
            else sd[n] = rsz(dvd[col]);
        }
        #pragma unroll
        for (int m = 0; m < 4; m++) {
            #pragma unroll
            for (int r = 0; r < 4; r++) {
                int row = rowb + m * 16 + r;
                float bias = BG[stream * 128 + row];
                #pragma unroll
                for (int n = 0; n < 4; n++) {
                    int col = colb + n * 16;
                    float v = acc[m][n][r] + bias;
                    if (stream == 0) {
                        GXp[(size_t)b * 131072 + ((size_t)row << 10) + col] = f2bf(v * sx[n]);
                        GBp[(size_t)b * 262144 + ((size_t)(row + 128) << 10) + col] = f2bf(v * sb_[n]);
                        GDp[(size_t)b * 262144 + ((size_t)(row + 128) << 10) + col] = f2bf(v * sd[n]);
                    } else if (stream == 1) {
                        GBp[(size_t)b * 262144 + ((size_t)row << 10) + col] = f2bf(v * sb_[n]);
                    } else {
                        GDp[(size_t)b * 262144 + ((size_t)row << 10) + col] = f2bf(v * sd[n]);
                    }
                }
            }
        }
    }
}

// ---------------------------------------------------------------------------
// Inner factor GEMM: M[c][j] = sum_n TPt[z][c][n] * Gd[j][n], row flip c^128.
// ---------------------------------------------------------------------------
__global__ __launch_bounds__(256) void inner_gemm(
    const u16* __restrict__ TPt, const u16* __restrict__ GXp,
    const u16* __restrict__ GBp, const u16* __restrict__ GDp,
    u16* __restrict__ MX, u16* __restrict__ MB, u16* __restrict__ MD)
{
    __shared__ alignas(16) u16 lsA[2 * 128 * 32];
    __shared__ alignas(16) u16 lsB[2 * 128 * 32];

    const int z = blockIdx.z, which = z >> 4, b = z & 15;
    if (which == 0 && blockIdx.y != 0) return;
    const u16* Gp = (which == 0) ? GXp : (which == 1) ? GBp : GDp;
    u16* M = (which == 0) ? MX : (which == 1) ? MB : MD;
    const int ldc = (which == 0) ? 128 : 256;
    const long long sB = (which == 0) ? 131072 : 262144;

    const u16* Ab = TPt + (size_t)z * 262144 + (size_t)(blockIdx.x * 128) * 1024;
    const u16* Bb = Gp + (size_t)b * sB + (size_t)(blockIdx.y * 128) * 1024;

    f32x4 acc[4][4] = {};
    gemm_core<128, 128, 2, 2>(Ab, nullptr, 1024, 1024, Bb, 1024, 1024, lsA, lsB, acc);

    const int lane = threadIdx.x & 63;
    const int wave = threadIdx.x >> 6;
    const int wr = wave >> 1, wc = wave & 1;
    const int rowb = blockIdx.x * 128 + (wr << 6) + ((lane >> 4) << 2);
    const int colb = blockIdx.y * 128 + (wc << 6) + (lane & 15);
    u16* Cb = M + (size_t)b * (256 * ldc);
    #pragma unroll
    for (int m = 0; m < 4; m++)
        #pragma unroll
        for (int n = 0; n < 4; n++)
            #pragma unroll
            for (int r = 0; r < 4; r++) {
                int row = (rowb + m * 16 + r) ^ 128;
                int col = colb + n * 16;
                Cb[(size_t)row * ldc + col] = f2bf(acc[m][n][r]);
            }
}

// ---------------------------------------------------------------------------
// Fold GEMM into pair-concatenated FF2 [pair][b][256][512]:
// q: 0=dd(pair0,s0) 1=bx(pair0,s1) 2=bb(pair1,s0) 3=dx(pair1,s1) 4=xx(pair2,s0)
// ---------------------------------------------------------------------------
__global__ __launch_bounds__(512) void fold_gemm(
    const u16* __restrict__ WF, const u16* __restrict__ MX,
    const u16* __restrict__ MB, const u16* __restrict__ MD,
    u16* __restrict__ FF2)
{
    __shared__ alignas(16) u16 lsA[2 * 128 * 32];
    __shared__ alignas(16) u16 lsB[2 * 256 * 32];

    const int z = blockIdx.z, q = z >> 4, b = z & 15;
    const int pair = (q >> 1) + (q == 4 ? 0 : 0) * 0 + ((q == 4) ? 2 : (q >> 1));
    const int pr = (q == 4) ? 2 : (q >> 1);
    const int side = (q == 1 || q == 3) ? 1 : 0;
    (void)pair;
    const u16* Mp = (q == 4) ? MX : (q == 1 || q == 2) ? MB : MD;
    const int coff = (q == 1 || q == 3) ? 128 : 0;
    const int ldb  = (q == 4) ? 128 : 256;

    const u16* Ab = WF + q * 32768 + (size_t)(blockIdx.x * 128) * 128;
    const u16* Bb = Mp + (size_t)b * (256 * ldb) + coff;

    f32x4 acc[4][4] = {};
    gemm_core<128, 256, 2, 4>(Ab, nullptr, 128, 128, Bb, ldb, 128, lsA, lsB, acc);

    const int lane = threadIdx.x & 63;
    const int wave = threadIdx.x >> 6;
    const int wr = wave >> 2, wc = wave & 3;
    const int rowb = blockIdx.x * 128 + wr * 64 + ((lane >> 4) << 2);
    const int colb = side * 256 + wc * 64 + (lane & 15);
    u16* Cb = FF2 + (size_t)pr * 2097152 + (size_t)b * 131072;
    #pragma unroll
    for (int m = 0; m < 4; m++)
        #pragma unroll
        for (int n = 0; n < 4; n++)
            #pragma unroll
            for (int r = 0; r < 4; r++)
                Cb[(size_t)(rowb + m * 16 + r) * 512 + colb + n * 16] = f2bf(acc[m][n][r]);
}

// ---------------------------------------------------------------------------
// Outer GEMM, single core per block with dual-A K-concat:
// zhi 0: s1 = [TPS_d | TPS_b] @ FF2[0]^T   (K=512)
// zhi 1: s2 = [TPS_b | TPS_d] @ FF2[1]^T   (K=512)
// zhi 2: xs =  TPS_x          @ FF2[2]^T   (K=256)
// ---------------------------------------------------------------------------
__global__ __launch_bounds__(512) void outer_gemm(
    const u16* __restrict__ TPS, const u16* __restrict__ FF2,
    u16* __restrict__ S1b, u16* __restrict__ S2b, u16* __restrict__ XSb)
{
    __shared__ alignas(16) u16 lsA[2 * 128 * 32];
    __shared__ alignas(16) u16 lsB[2 * 256 * 32];

    const int z = blockIdx.z, zhi = z >> 4, b = z & 15;
    const int sa1[3] = {2, 1, 0}, sa2[3] = {1, 2, 0};
    const int K = (zhi == 2) ? 256 : 512;

    const u16* A1 = TPS + (size_t)(sa1[zhi] * 16 + b) * 262144 + (size_t)(blockIdx.x * 128) * 256;
    const u16* A2 = (zhi == 2) ? nullptr
                  : TPS + (size_t)(sa2[zhi] * 16 + b) * 262144 + (size_t)(blockIdx.x * 128) * 256;
    const u16* Bb = FF2 + (size_t)zhi * 2097152 + (size_t)b * 131072;

    f32x4 acc[4][4] = {};
    gemm_core<128, 256, 2, 4>(A1, A2, 256, 256, Bb, 512, K, lsA, lsB, acc);

    const int lane = threadIdx.x & 63;
    const int wave = threadIdx.x >> 6;
    const int wr = wave >> 2, wc = wave & 3;
    const int rowb = blockIdx.x * 128 + wr * 64 + ((lane >> 4) << 2);
    const int colb = wc * 64 + (lane & 15);
    u16* Cb = ((zhi == 0) ? S1b : (zhi == 1) ? S2b : XSb) + (size_t)b * 262144;
    #pragma unroll
    for (int m = 0; m < 4; m++)
        #pragma unroll
        for (int n = 0; n < 4; n++)
            #pragma unroll
            for (int r = 0; r < 4; r++)
                Cb[(size_t)(rowb + m * 16 + r) * 256 + colb + n * 16] = f2bf(acc[m][n][r]);
}

// ---------------------------------------------------------------------------
// prep + transpose merged. z<48: transpose x/ob/od -> XT. z==48: weight prep
// + zero the atomic-accumulated region ZZ (CS|DINV|BNA, 62464 floats).
// ---------------------------------------------------------------------------
__global__ void prep_transpose(const float* __restrict__ x, const float* __restrict__ ob,
                               const float* __restrict__ od, u16* __restrict__ xt,
                               const float* Wt, const float* Wp,
                               const float* Wgx, const float* Wgb, const float* Wgd,
                               const float* bgx, const float* bgb, const float* bgd,
                               const float* Wwd, const float* Wwxb, const float* Wwb,
                               const float* Wwxd, const float* Wwx, const float* Wout,
                               u16* wtp, u16* wg, u16* wf, u16* wout, float* bg,
                               float* __restrict__ ZZ)
{
    int tx = threadIdx.x, ty = threadIdx.y;
    if (blockIdx.z == 48) {
        int t = (blockIdx.y * 32 + blockIdx.x) * 256 + ty * 32 + tx;   // 0..65535
        wtp[t]  = f2bf(t < 32768 ? Wt[t] : Wp[t - 32768]);
        wout[t] = f2bf(Wout[t]);
        if (t < 32768) {
            wg[t] = f2bf(Wgx[t]); wg[32768 + t] = f2bf(Wgb[t]); wg[65536 + t] = f2bf(Wgd[t]);
            wf[t]          = f2bf(0.5f * Wwd[t]);
            wf[32768 + t]  = f2bf(0.5f * Wwxb[t]);
            wf[65536 + t]  = f2bf(0.5f * Wwb[t]);
            wf[98304 + t]  = f2bf(0.5f * Wwxd[t]);
            wf[131072 + t] = f2bf(0.5f * Wwx[t]);
        }
        if (t < 384) bg[t] = (t < 128) ? bgx[t] : (t < 256) ? bgb[t - 128] : bgd[t - 256];
        if (t < 62464) ZZ[t] = 0.0f;
        return;
    }
    __shared__ float tbuf[32][33];
    int z = blockIdx.z, which = z >> 4, b = z & 15;
    const float* src = (which == 0) ? x : (which == 1) ? ob : od;
    const float* s = src + (size_t)b * cC * cN;
    u16* dst = xt + (size_t)which * (cB * cN * cC) + (size_t)b * (cN * cC);
    int n0 = blockIdx.x << 5, c0 = blockIdx.y << 5;
    #pragma unroll
    for (int i = 0; i < 4; i++) { int r = ty + (i << 3); tbuf[r][tx] = s[(size_t)(c0 + r) * cN + n0 + tx]; }
    __syncthreads();
    #pragma unroll
    for (int i = 0; i < 4; i++) { int r = ty + (i << 3); dst[(size_t)(n0 + r) * cC + c0 + tx] = f2bf(tbuf[tx][r]); }
}

// ---------------------------------------------------------------------------
// Degree matvec (raw d, atomic): DINV[z][n] += sum_c TPt[z][c][n]*ws[c]
// ---------------------------------------------------------------------------
__global__ void dinv_partial(const u16* __restrict__ TPt, const float* __restrict__ CS,
                             float* __restrict__ DINV)
{
    int z = blockIdx.y;
    int cq = blockIdx.z;
    int n = blockIdx.x * 256 + threadIdx.x;
    __shared__ float ws[64];
    if (threadIdx.x < 64) {
        int c = cq * 64 + threadIdx.x;
        ws[threadIdx.x] = 0.5f * CS[z * 256 + (c ^ 128)];
    }
    __syncthreads();
    const u16* base = TPt + (size_t)z * 262144 + (size_t)(cq * 64) * 1024 + n;
    float d = 0;
    #pragma unroll 16
    for (int c = 0; c < 64; c++) d += bf2f(base[(size_t)c << 10]) * ws[c];
    atomicAdd(&DINV[(z << 10) + n], d);
}

// ---------------------------------------------------------------------------
__global__ void bn_stats(const u16* __restrict__ s1, const u16* __restrict__ s2,
                         float* __restrict__ acc)
{
    int c = threadIdx.x;
    const u16* s = blockIdx.y ? s2 : s1;
    float* a = acc + blockIdx.y * 512;
    size_t r0 = (size_t)blockIdx.x * 64;
    float sum = 0, sq = 0;
    for (int r = 0; r < 64; r++) { float v = bf2f(s[(r0 + r) * 256 + c]); sum += v; sq += v * v; }
    atomicAdd(&a[c], sum);
    atomicAdd(&a[256 + c], sq);
}

// combine + BN finalize: pre = bn1(s1)+bn2(s2)+xs+bwx -> bf16
__global__ void combine_kernel(const u16* __restrict__ s1, const u16* __restrict__ s2,
                               const u16* __restrict__ xs, const float* __restrict__ BNA,
                               const float* __restrict__ g1, const float* __restrict__ be1,
                               const float* __restrict__ g2, const float* __restrict__ be2,
                               const float* __restrict__ bwx, u16* __restrict__ pre)
{
    size_t t = (size_t)blockIdx.x * 256 + threadIdx.x;
    size_t base = t << 3;
    int c0 = (int)(base & 255);
    short8 a = *(const short8*)(s1 + base);
    short8 b = *(const short8*)(s2 + base);
    short8 cx = *(const short8*)(xs + base);
    const float inv = 1.0f / 16384.0f;
    short8 o;
    #pragma unroll
    for (int j = 0; j < 8; j++) {
        int c = c0 + j;
        float m1 = BNA[c] * inv;
        float v1 = BNA[256 + c] * inv - m1 * m1;
        float sc1 = g1[c] * rsqrtf(v1 + 1e-5f);
        float sh1 = be1[c] - m1 * sc1;
        float m2 = BNA[512 + c] * inv;
        float v2 = BNA[768 + c] * inv - m2 * m2;
        float sc2 = g2[c] * rsqrtf(v2 + 1e-5f);
        float sh2 = be2[c] - m2 * sc2;
        float v = sc1 * bf2f((u16)a[j]) + sh1 + sc2 * bf2f((u16)b[j]) + sh2
                + bf2f((u16)cx[j]) + bwx[c];
        o[j] = (short)f2bf(v);
    }
    *(short8*)(pre + base) = o;
}

// ---------------------------------------------------------------------------
extern "C" void kernel_launch(void* const* d_in, const int* in_sizes, int n_in,
                              void* d_out, int out_size, void* d_ws, size_t ws_size,
                              hipStream_t stream)
{
    const float* x    = (const float*)d_in[0];
    const float* ob   = (const float*)d_in[1];
    const float* od   = (const float*)d_in[2];
    const float* Wt   = (const float*)d_in[3];
    const float* Wp   = (const float*)d_in[4];
    const float* Wgx  = (const float*)d_in[5];
    const float* bgx  = (const float*)d_in[6];
    const float* Wgb  = (const float*)d_in[7];
    const float* bgb  = (const float*)d_in[8];
    const float* Wgd  = (const float*)d_in[9];
    const float* bgd  = (const float*)d_in[10];
    const float* Wwx  = (const float*)d_in[11];
    const float* bwx  = (const float*)d_in[12];
    const float* Wwb  = (const float*)d_in[13];
    const float* Wwd  = (const float*)d_in[15];
    const float* Wwxb = (const float*)d_in[17];
    const float* Wwxd = (const float*)d_in[19];
    const float* g1   = (const float*)d_in[21];
    const float* be1  = (const float*)d_in[22];
    const float* g2   = (const float*)d_in[23];
    const float* be2  = (const float*)d_in[24];
    const float* Wout = (const float*)d_in[25];
    const float* bout = (const float*)d_in[26];
    float* out = (float*)d_out;

    char* w = (char*)d_ws;
    u16*   XT   = (u16*)(w);                    // [3][16][1024][256]  25165824 B
    u16*   TPt  = (u16*)(w + 25165824);         // [3][16][256][1024]  25165824 B (reused as PRE)
    u16*   TPS  = (u16*)(w + 50331648);         // [3][16][1024][256]  25165824 B
    u16*   GXp  = (u16*)(w + 75497472);         // [16][128][1024]     4194304 B
    u16*   GBp  = (u16*)(w + 79691776);         // [16][256][1024]     8388608 B
    u16*   GDp  = (u16*)(w + 88080384);         // [16][256][1024]     8388608 B
    u16*   MX   = (u16*)(w + 96468992);         // [16][256][128]      1048576 B
    u16*   MB   = (u16*)(w + 97517568);         // [16][256][256]      2097152 B
    u16*   MD   = (u16*)(w + 99614720);         // [16][256][256]      2097152 B
    u16*   FF2  = (u16*)(w + 101711872);        // [3][16][256][512]   12582912 B
    u16*   S1b  = (u16*)(w + 114294784);        // [16][1024][256]     8388608 B
    u16*   S2b  = (u16*)(w + 122683392);        // 8388608 B
    u16*   XSb  = (u16*)(w + 131072000);        // 8388608 B
    u16*   WTP  = (u16*)(w + 139460608);        // 131072 B
    u16*   WG   = (u16*)(w + 139591680);        // 196608 B
    u16*   WF   = (u16*)(w + 139788288);        // 327680 B
    u16*   WOUT = (u16*)(w + 140115968);        // 131072 B
    float* BGf  = (float*)(w + 140247040);      // 2048 B
    float* ZZ   = (float*)(w + 140249088);      // 249856 B  (CS | DINV | BNA)

    float* CS   = ZZ;                 // [48][256]
    float* DINV = ZZ + 12288;         // [3][16][1024]
    float* BNA  = ZZ + 61440;         // [1024]
    u16*   PRE  = TPt;                // TPt dead after inner_gemm

    // 1. prep + transpose + zero atomics region
    prep_transpose<<<dim3(32, 8, 49), dim3(32, 8), 0, stream>>>(
        x, ob, od, XT, Wt, Wp, Wgx, Wgb, Wgd, bgx, bgb, bgd,
        Wwd, Wwxb, Wwb, Wwxd, Wwx, Wout, WTP, WG, WF, WOUT, BGf, ZZ);

    // 2. TPt = relu(WTP @ XT^T), fused column sums -> CS
    gemm_bt<128, 256, 2, 4, true, true, false, false, true><<<dim3(2, 4, 48), 512, 0, stream>>>(
        WTP, 0, 0, 256,  XT, 262144, 4194304, 256,  TPt, 262144, 4194304, 1024,
        256, nullptr, 0, nullptr, 0, CS, 256);

    // 3. degree matvec (raw d)
    dinv_partial<<<dim3(4, 48, 4), 256, 0, stream>>>(TPt, CS, DINV);

    // 4. TPS (dinv-scaled TP) + scaled G, one dispatch
    phase2<<<dim3(576), 512, 0, stream>>>(XT, WTP, WG, BGf, DINV, TPS, GXp, GBp, GDp);

    // 5. inner factors M = TPt @ G^T (K=1024), row-flipped
    inner_gemm<<<dim3(2, 2, 48), 256, 0, stream>>>(TPt, GXp, GBp, GDp, MX, MB, MD);

    // 6. folds -> FF2 pair-concat
    fold_gemm<<<dim3(2, 1, 80), 512, 0, stream>>>(WF, MX, MB, MD, FF2);

    // 7. outers (single dual-A core each)
    outer_gemm<<<dim3(8, 1, 48), 512, 0, stream>>>(TPS, FF2, S1b, S2b, XSb);

    // 8. BN stats
    bn_stats<<<dim3(256, 2), 256, 0, stream>>>(S1b, S2b, BNA);

    // 9. combine (+ BN finalize)
    combine_kernel<<<dim3(2048), 256, 0, stream>>>(S1b, S2b, XSb, BNA,
        g1, be1, g2, be2, bwx, PRE);

    // 10. out = Wout @ pre + bout + x
    gemm_bt<128, 256, 2, 4, false, false, true, true, false><<<dim3(2, 4, 16), 512, 0, stream>>>(
        WOUT, 0, 0, 256,  PRE, 262144, 0, 256,  out, 262144, 0, 1024,
        256, bout, 0, x, 262144, nullptr, 0);
}